// Round 2
// baseline (225.134 us; speedup 1.0000x reference)
//
#include <hip/hip_runtime.h>
#include <hip/hip_bf16.h>
#include <math.h>

// ---------------- types ----------------
typedef short s16x8 __attribute__((ext_vector_type(8)));
typedef float f32x4 __attribute__((ext_vector_type(4)));

// ---------------- fp32 <-> bf16 ----------------
__device__ inline unsigned short f2bf(float x) {
    unsigned int u = __float_as_uint(x);
    unsigned int r = (u + 0x7fffu + ((u >> 16) & 1u)) >> 16;
    return (unsigned short)r;
}
__device__ inline float bf2f(unsigned short u) {
    return __uint_as_float(((unsigned int)u) << 16);
}

// fast tanh: 1 - 2/(exp(2x)+1); saturates correctly at +-inf
__device__ inline float fast_tanh(float x) {
    float e = __expf(2.0f * x);
    return 1.0f - 2.0f * __builtin_amdgcn_rcpf(e + 1.0f);
}

// ---------------- fused: cvt x, cvt W_ih, pack W_lin -> bf16 [16][2336] ------
__global__ void cvtprep_kernel(const float* __restrict__ x,
                               const float* __restrict__ W_ih,
                               const float* __restrict__ W_lin,
                               unsigned short* __restrict__ xb,
                               unsigned short* __restrict__ wb,
                               unsigned short* __restrict__ wlb) {
    int blk = blockIdx.x;
    int tid = threadIdx.x;
    if (blk < 16384) {
        int i = blk * 256 + tid;
        float4 v = ((const float4*)x)[i];
        ushort4 o; o.x = f2bf(v.x); o.y = f2bf(v.y); o.z = f2bf(v.z); o.w = f2bf(v.w);
        ((ushort4*)xb)[i] = o;
    } else if (blk < 20480) {
        int i = (blk - 16384) * 256 + tid;
        float4 v = ((const float4*)W_ih)[i];
        ushort4 o; o.x = f2bf(v.x); o.y = f2bf(v.y); o.z = f2bf(v.z); o.w = f2bf(v.w);
        ((ushort4*)wb)[i] = o;
    } else {
        int idx = (blk - 20480) * 256 + tid;   // 16*2336 = 37376
        if (idx < 37376) {
            int c = idx / 2336, k = idx - c * 2336;
            float v = (c < 10 && k < 2318) ? W_lin[c * 2318 + k] : 0.f;
            wlb[idx] = f2bf(v);
        }
    }
}

// ---------------- GEMM: Hb = bf16(tanh(x @ W_ih^T + b)) ----------------
// 256x256 tile, BK=64, 512 thr (2x4 waves, 128x64 C each).
// Balanced 4-phase schedule (8/4/8/4 ds_reads):
//   p1: B ks0 (4) + A lo ks0 (4) | stage t+1 A-bot + t+1 B-h1 -> buf^1
//   p2: A hi ks0 (4)
//   p3: B ks1 (4) + A lo ks1 (4)
//   p4: A hi ks1 (4)             | stage t+2 B-h0 + t+2 A-top -> buf
//       boundary s_waitcnt vmcnt(4): drains ALL of t+1's 8 units (4 from
//       t-1 p4 + 4 from t p1), leaves t+2's 4 in flight.
// Stage-region safety: p1 targets buf^1 (unread during t); p4 targets
// LA rows0-63 / LB h0, whose last readers (p3) passed a barrier.
// XCD map: 4 rblk x 8 cblk per XCD -> 4MB A (L2-fit) + 8MB B per XCD.

#define MFMA_(a, b, c) __builtin_amdgcn_mfma_f32_16x16x32_bf16(a, b, c, 0, 0, 0)

__device__ inline s16x8 frag_ld(const unsigned short* hbase, int row, int ksub, int quad) {
    int slot = (ksub * 4 + quad) ^ (row & 7);
    return *(const s16x8*)(hbase + row * 64 + slot * 8);
}

// stage one 8KB unit: 64 rows x 64 cols bf16, 1x16B load per thread
__device__ inline void stage_u(const unsigned short* __restrict__ gmat, int half,
                               int rowoff, int kt, unsigned short* lmat, int tid) {
    int r = tid >> 3, s = tid & 7;
    int lr = rowoff + r;
    int ks = (s ^ (lr & 7)) << 3;
    const unsigned short* gp = gmat + (size_t)(half * 128 + lr) * 2048 + kt * 64 + ks;
    __builtin_amdgcn_global_load_lds(
        (const __attribute__((address_space(1))) void*)gp,
        (__attribute__((address_space(3))) void*)(lmat + half * 8192 + lr * 64 + s * 8),
        16, 0, 0);
}

#define LOAD_B(ks)                                                       \
    b0 = frag_ld(Bh, bco +  0 + mrow, (ks), quad);                       \
    b1 = frag_ld(Bh, bco + 16 + mrow, (ks), quad);                       \
    b2 = frag_ld(Bh, bco + 32 + mrow, (ks), quad);                       \
    b3 = frag_ld(Bh, bco + 48 + mrow, (ks), quad);

#define LOAD_A(h, ks)                                                    \
    af0 = frag_ld(Ah, (h) * 64 +  0 + mrow, (ks), quad);                 \
    af1 = frag_ld(Ah, (h) * 64 + 16 + mrow, (ks), quad);                 \
    af2 = frag_ld(Ah, (h) * 64 + 32 + mrow, (ks), quad);                 \
    af3 = frag_ld(Ah, (h) * 64 + 48 + mrow, (ks), quad);

#define MFMA_H(hh)                                                       \
    acc[(hh)*4 + 0][0] = MFMA_(af0, b0, acc[(hh)*4 + 0][0]);             \
    acc[(hh)*4 + 0][1] = MFMA_(af0, b1, acc[(hh)*4 + 0][1]);             \
    acc[(hh)*4 + 0][2] = MFMA_(af0, b2, acc[(hh)*4 + 0][2]);             \
    acc[(hh)*4 + 0][3] = MFMA_(af0, b3, acc[(hh)*4 + 0][3]);             \
    acc[(hh)*4 + 1][0] = MFMA_(af1, b0, acc[(hh)*4 + 1][0]);             \
    acc[(hh)*4 + 1][1] = MFMA_(af1, b1, acc[(hh)*4 + 1][1]);             \
    acc[(hh)*4 + 1][2] = MFMA_(af1, b2, acc[(hh)*4 + 1][2]);             \
    acc[(hh)*4 + 1][3] = MFMA_(af1, b3, acc[(hh)*4 + 1][3]);             \
    acc[(hh)*4 + 2][0] = MFMA_(af2, b0, acc[(hh)*4 + 2][0]);             \
    acc[(hh)*4 + 2][1] = MFMA_(af2, b1, acc[(hh)*4 + 2][1]);             \
    acc[(hh)*4 + 2][2] = MFMA_(af2, b2, acc[(hh)*4 + 2][2]);             \
    acc[(hh)*4 + 2][3] = MFMA_(af2, b3, acc[(hh)*4 + 2][3]);             \
    acc[(hh)*4 + 3][0] = MFMA_(af3, b0, acc[(hh)*4 + 3][0]);             \
    acc[(hh)*4 + 3][1] = MFMA_(af3, b1, acc[(hh)*4 + 3][1]);             \
    acc[(hh)*4 + 3][2] = MFMA_(af3, b2, acc[(hh)*4 + 3][2]);             \
    acc[(hh)*4 + 3][3] = MFMA_(af3, b3, acc[(hh)*4 + 3][3]);

#define PHASE_CORE(hh)                                                   \
    __builtin_amdgcn_s_barrier();                                        \
    asm volatile("s_waitcnt lgkmcnt(0)" ::: "memory");                   \
    __builtin_amdgcn_s_setprio(1);                                       \
    MFMA_H(hh);                                                          \
    __builtin_amdgcn_s_setprio(0);

__global__ __launch_bounds__(512) void gemm_tanh_kernel(
    const unsigned short* __restrict__ A, const unsigned short* __restrict__ Bm,
    const float* __restrict__ b_ih, const float* __restrict__ b_hh,
    unsigned short* __restrict__ Hb)
{
    __shared__ __align__(16) unsigned short lds[2][2][16384];  // [buf][A/B][half*128*64]

    const int tid  = threadIdx.x;
    const int lane = tid & 63;
    const int wave = tid >> 6;
    const int wgid = blockIdx.x;
    // XCD map: hw xcd = wgid & 7. Give each XCD a 4x8 (rblk x cblk) sub-grid:
    // unique bytes/XCD = 4MB A (L2-resident) + 8MB B.
    const int xcd  = wgid & 7;
    const int idx  = wgid >> 3;          // 0..31
    const int rblk = xcd * 4 + (idx & 3);
    const int cblk = idx >> 2;           // 0..7
    const int row0 = rblk * 256;
    const int col0 = cblk * 256;
    const int wm   = wave >> 2;   // 0..1 : A half / 128-row block
    const int wn   = wave & 3;    // 0..3 : 64-col block
    const int quad = lane >> 4;
    const int mrow = lane & 15;
    const int NT   = 32;          // K tiles of 64

    const unsigned short* Ag = A  + (size_t)row0 * 2048;
    const unsigned short* Bg = Bm + (size_t)col0 * 2048;

    f32x4 acc[8][4];
#pragma unroll
    for (int i = 0; i < 8; ++i)
#pragma unroll
        for (int j = 0; j < 4; ++j) acc[i][j] = f32x4{0.f, 0.f, 0.f, 0.f};

    // prologue: tile0 fully (8 units), then tile1's "p4 portion":
    // B-h0 + A-top (4 units) -> lds[1]
    stage_u(Ag, 0, 0,  0, lds[0][0], tid);  stage_u(Ag, 0, 64, 0, lds[0][0], tid);
    stage_u(Ag, 1, 0,  0, lds[0][0], tid);  stage_u(Ag, 1, 64, 0, lds[0][0], tid);
    stage_u(Bg, 0, 0,  0, lds[0][1], tid);  stage_u(Bg, 0, 64, 0, lds[0][1], tid);
    stage_u(Bg, 1, 0,  0, lds[0][1], tid);  stage_u(Bg, 1, 64, 0, lds[0][1], tid);
    stage_u(Bg, 0, 0,  1, lds[1][1], tid);  stage_u(Bg, 0, 64, 1, lds[1][1], tid);
    stage_u(Ag, 0, 0,  1, lds[1][0], tid);  stage_u(Ag, 1, 0,  1, lds[1][0], tid);
    asm volatile("s_waitcnt vmcnt(4)" ::: "memory");  // tile0 resident
    __builtin_amdgcn_s_barrier();

    for (int t = 0; t < NT; ++t) {
        const int buf = t & 1;
        unsigned short* LA  = lds[buf][0];
        unsigned short* LB  = lds[buf][1];
        unsigned short* NLA = lds[buf ^ 1][0];
        unsigned short* NLB = lds[buf ^ 1][1];
        const unsigned short* Ah = LA + wm * 8192;
        const unsigned short* Bh = LB + (wn >> 1) * 8192;
        const int bco = (wn & 1) * 64;

        s16x8 b0, b1, b2, b3;
        s16x8 af0, af1, af2, af3;

        // ===== phase 1: B ks0 + A lo ks0 | stage t+1 A-bot + t+1 B-h1 =====
        LOAD_B(0);
        LOAD_A(0, 0);
        if (t + 1 < NT) {
            stage_u(Ag, 0, 64, t + 1, NLA, tid);
            stage_u(Ag, 1, 64, t + 1, NLA, tid);
            stage_u(Bg, 1, 0,  t + 1, NLB, tid);
            stage_u(Bg, 1, 64, t + 1, NLB, tid);
        }
        asm volatile("s_waitcnt lgkmcnt(4)" ::: "memory");  // B ks0 done
        PHASE_CORE(0);
        __builtin_amdgcn_s_barrier();

        // ===== phase 2: A hi ks0 =====
        LOAD_A(1, 0);
        PHASE_CORE(1);
        __builtin_amdgcn_s_barrier();

        // ===== phase 3: B ks1 + A lo ks1 =====
        LOAD_B(1);
        LOAD_A(0, 1);
        asm volatile("s_waitcnt lgkmcnt(4)" ::: "memory");  // B ks1 done
        PHASE_CORE(0);
        __builtin_amdgcn_s_barrier();

        // ===== phase 4: A hi ks1 | stage t+2 B-h0 + t+2 A-top; boundary =====
        LOAD_A(1, 1);
        if (t + 2 < NT) {
            stage_u(Bg, 0, 0,  t + 2, LB, tid);
            stage_u(Bg, 0, 64, t + 2, LB, tid);
            stage_u(Ag, 0, 0,  t + 2, LA, tid);
            stage_u(Ag, 1, 0,  t + 2, LA, tid);
        }
        PHASE_CORE(1);
        if (t + 2 < NT) {
            asm volatile("s_waitcnt vmcnt(4)" ::: "memory");   // t+1 resident
        } else if (t + 1 < NT) {
            asm volatile("s_waitcnt vmcnt(0)" ::: "memory");   // final drain
        }
        __builtin_amdgcn_s_barrier();
    }

    float bias[4];
#pragma unroll
    for (int j = 0; j < 4; ++j) {
        int gc = col0 + wn * 64 + j * 16 + mrow;
        bias[j] = b_ih[gc] + b_hh[gc];
    }
#pragma unroll
    for (int i = 0; i < 8; ++i) {
#pragma unroll
        for (int rr = 0; rr < 4; ++rr) {
            int grow = row0 + wm * 128 + i * 16 + quad * 4 + rr;
#pragma unroll
            for (int j = 0; j < 4; ++j) {
                int gc = col0 + wn * 64 + j * 16 + mrow;
                float v = acc[i][j][rr] + bias[j];
                Hb[(size_t)grow * 2048 + gc] = f2bf(fast_tanh(v));
            }
        }
    }
}

// ---------------- AvgPool1d(k=45,s=45): 8 rows/block, coalesced f-major out --
__global__ __launch_bounds__(256) void pool_kernel(
    const unsigned short* __restrict__ Hb, float* __restrict__ pooled_t) {
    __shared__ unsigned short hs[8 * 2048];  // 32 KB
    __shared__ float outs[45 * 8];
    int b0 = blockIdx.x * 8;
    int tid = threadIdx.x;
    const ushort4* src = (const ushort4*)(Hb + (size_t)b0 * 2048);
    ushort4* dst = (ushort4*)hs;
    for (int i = tid; i < 4096; i += 256) dst[i] = src[i];
    __syncthreads();
    for (int o = tid; o < 360; o += 256) {
        int f = o % 45, r = o / 45;
        const unsigned short* row = hs + r * 2048 + f * 45;
        float s = 0.f;
#pragma unroll
        for (int k = 0; k < 45; ++k) s += bf2f(row[k]);
        outs[f * 8 + r] = s * (1.0f / 45.0f);
    }
    __syncthreads();
    for (int o = tid; o < 360; o += 256) {
        int f = o >> 3, r = o & 7;
        pooled_t[f * 8192 + b0 + r] = outs[o];
    }
}

// ---------------- per-feature dual prefix sum (sum, sum^2), single pass ------
__global__ __launch_bounds__(256) void scan_kernel(
    const float* __restrict__ pooled_t,
    float* __restrict__ cs_t, float* __restrict__ cs2_t) {
    __shared__ float t1[256], t2[256];
    int f = blockIdx.x;
    int tid = threadIdx.x;
    const float* p = pooled_t + f * 8192;
    int base = tid * 32;
    float loc[32];
    float s1 = 0.f, s2 = 0.f;
#pragma unroll
    for (int i = 0; i < 32; ++i) {
        float v = p[base + i];
        loc[i] = v; s1 += v; s2 += v * v;
    }
    t1[tid] = s1; t2[tid] = s2;
    __syncthreads();
    for (int d = 1; d < 256; d <<= 1) {
        float a1 = (tid >= d) ? t1[tid - d] : 0.f;
        float a2 = (tid >= d) ? t2[tid - d] : 0.f;
        __syncthreads();
        t1[tid] += a1; t2[tid] += a2;
        __syncthreads();
    }
    float r1 = t1[tid] - s1, r2 = t2[tid] - s2;  // exclusive offsets
    float* c1 = cs_t + f * 8192;
    float* c2 = cs2_t + f * 8192;
#pragma unroll
    for (int i = 0; i < 32; ++i) {
        float v = loc[i];
        r1 += v; r2 += v * v;
        c1[base + i] = r1; c2[base + i] = r2;
    }
}

// ---------------- final: MFMA GEMM [Hb|est](8192x2336) @ Wb^T(16x2336) -------
#define ESTRIDE 290
__global__ __launch_bounds__(256) void final_kernel(
    const unsigned short* __restrict__ Hb,
    const float* __restrict__ cs_t, const float* __restrict__ cs2_t,
    const unsigned short* __restrict__ Wb, const float* __restrict__ b_lin,
    float* __restrict__ out) {
    __shared__ unsigned short Es[32 * ESTRIDE];  // 18.1 KB
    __shared__ float comb[2 * 16 * 17];          // 2.1 KB
    int tid = threadIdx.x;
    int lane = tid & 63;
    int wave = tid >> 6;
    int b0 = blockIdx.x * 32;

    // build est tile: (f,j,r) -> mean/var from prefix sums (all L2-hot)
    for (int i = tid; i < 135 * 32; i += 256) {
        int fj = i >> 5, r = i & 31;
        int f = fj / 3, j = fj - 3 * f;
        int b = b0 + r;
        int L = (j == 0) ? 32 : (j == 1) ? 128 : 512;
        const float* c1 = cs_t + f * 8192;
        const float* c2 = cs2_t + f * 8192;
        float a1 = c1[b], a2 = c2[b];
        float p1 = 0.f, p2 = 0.f;
        if (b >= L) { p1 = c1[b - L]; p2 = c2[b - L]; }
        float cnt = (float)((b + 1 < L) ? (b + 1) : L);
        float m = (a1 - p1) / cnt;
        float v = (a2 - p2) / cnt - m * m;
        int d0 = f * 6 + j * 2;
        Es[r * ESTRIDE + d0]     = f2bf(m);
        Es[r * ESTRIDE + d0 + 1] = f2bf(v);
    }
    // zero pad d in [270, 288)
    for (int i = tid; i < 32 * 18; i += 256) {
        int r = i / 18, d = 270 + i % 18;
        Es[r * ESTRIDE + d] = 0;
    }
    __syncthreads();

    const int t = wave >> 1;
    const int kh = wave & 1;
    const int quad = lane >> 4;
    const int mrow = lane & 15;
    const int rowt = b0 + t * 16;

    f32x4 acc = f32x4{0.f, 0.f, 0.f, 0.f};
    const unsigned short* arow = Hb + (size_t)(rowt + mrow) * 2048 + kh * 1024 + quad * 8;
    const unsigned short* brow = Wb + (size_t)mrow * 2336 + kh * 1024 + quad * 8;
#pragma unroll 4
    for (int k = 0; k < 1024; k += 32) {
        s16x8 a = *(const s16x8*)(arow + k);
        s16x8 b = *(const s16x8*)(brow + k);
        acc = __builtin_amdgcn_mfma_f32_16x16x32_bf16(a, b, acc, 0, 0, 0);
    }
    if (kh) {
        const unsigned short* erow = Es + (t * 16 + mrow) * ESTRIDE + quad * 8;
        const unsigned short* wrow = Wb + (size_t)mrow * 2336 + 2048 + quad * 8;
#pragma unroll
        for (int k = 0; k < 288; k += 32) {
            s16x8 a = *(const s16x8*)(erow + k);
            s16x8 b = *(const s16x8*)(wrow + k);
            acc = __builtin_amdgcn_mfma_f32_16x16x32_bf16(a, b, acc, 0, 0, 0);
        }
    }

    float* cb = comb + t * 272;
    if (kh == 0) {
#pragma unroll
        for (int r = 0; r < 4; ++r) cb[(quad * 4 + r) * 17 + mrow] = acc[r];
    }
    __syncthreads();
    if (kh == 1) {
#pragma unroll
        for (int r = 0; r < 4; ++r) cb[(quad * 4 + r) * 17 + mrow] += acc[r];
    }
    __syncthreads();

    if (tid < 32) {
        const float* base = comb + (tid >> 4) * 272 + (tid & 15) * 17;
        float lg[10];
        float mx = -1e30f;
#pragma unroll
        for (int c = 0; c < 10; ++c) {
            lg[c] = base[c] + b_lin[c];
            mx = fmaxf(mx, lg[c]);
        }
        float s = 0.f;
#pragma unroll
        for (int c = 0; c < 10; ++c) { lg[c] = expf(lg[c] - mx); s += lg[c]; }
        float inv = 1.0f / s;
#pragma unroll
        for (int c = 0; c < 10; ++c) out[(size_t)(b0 + tid) * 10 + c] = lg[c] * inv;
    }
}

// ---------------- launch ----------------
extern "C" void kernel_launch(void* const* d_in, const int* in_sizes, int n_in,
                              void* d_out, int out_size, void* d_ws, size_t ws_size,
                              hipStream_t stream) {
    const float* x     = (const float*)d_in[0];   // (8192,1,2048)
    const float* W_ih  = (const float*)d_in[1];   // (2048,2048)
    // d_in[2] = W_hh unused: h0 == 0 so the recurrent term vanishes
    const float* b_ih  = (const float*)d_in[3];
    const float* b_hh  = (const float*)d_in[4];
    const float* W_lin = (const float*)d_in[5];   // (10, 2318)
    const float* b_lin = (const float*)d_in[6];
    float* out = (float*)d_out;

    char* ws = (char*)d_ws;
    unsigned short* xb  = (unsigned short*)(ws);                 // 33554432 B
    unsigned short* wb  = (unsigned short*)(ws + 33554432);      //  8388608 B
    unsigned short* Hb  = (unsigned short*)(ws + 41943040);      // 33554432 B
    float* pooled_t     = (float*)(ws + 75497472);               //  1474560 B
    float* cs_t         = (float*)(ws + 76972032);               //  1474560 B
    float* cs2_t        = (float*)(ws + 78446592);               //  1474560 B
    unsigned short* wlb = (unsigned short*)(ws + 79921152);      //    74752 B (~80 MB)

    cvtprep_kernel<<<20626, 256, 0, stream>>>(x, W_ih, W_lin, xb, wb, wlb);
    gemm_tanh_kernel<<<256, 512, 0, stream>>>(xb, wb, b_ih, b_hh, Hb);
    pool_kernel<<<1024, 256, 0, stream>>>(Hb, pooled_t);
    scan_kernel<<<45, 256, 0, stream>>>(pooled_t, cs_t, cs2_t);
    final_kernel<<<256, 256, 0, stream>>>(Hb, cs_t, cs2_t, wlb, b_lin, out);
}

// Round 3
// 217.788 us; speedup vs baseline: 1.0337x; 1.0337x over previous
//
#include <hip/hip_runtime.h>
#include <hip/hip_bf16.h>
#include <math.h>

// ---------------- types ----------------
typedef short s16x8 __attribute__((ext_vector_type(8)));
typedef float f32x4 __attribute__((ext_vector_type(4)));

// ---------------- fp32 <-> bf16 ----------------
__device__ inline unsigned short f2bf(float x) {
    unsigned int u = __float_as_uint(x);
    unsigned int r = (u + 0x7fffu + ((u >> 16) & 1u)) >> 16;
    return (unsigned short)r;
}
__device__ inline float bf2f(unsigned short u) {
    return __uint_as_float(((unsigned int)u) << 16);
}

// fast tanh: 1 - 2/(exp(2x)+1); saturates correctly at +-inf
__device__ inline float fast_tanh(float x) {
    float e = __expf(2.0f * x);
    return 1.0f - 2.0f * __builtin_amdgcn_rcpf(e + 1.0f);
}

// ---------------- fused: cvt x, cvt W_ih, pack W_lin -> bf16 [16][2336] ------
__global__ void cvtprep_kernel(const float* __restrict__ x,
                               const float* __restrict__ W_ih,
                               const float* __restrict__ W_lin,
                               unsigned short* __restrict__ xb,
                               unsigned short* __restrict__ wb,
                               unsigned short* __restrict__ wlb) {
    int blk = blockIdx.x;
    int tid = threadIdx.x;
    if (blk < 16384) {
        int i = blk * 256 + tid;
        float4 v = ((const float4*)x)[i];
        ushort4 o; o.x = f2bf(v.x); o.y = f2bf(v.y); o.z = f2bf(v.z); o.w = f2bf(v.w);
        ((ushort4*)xb)[i] = o;
    } else if (blk < 20480) {
        int i = (blk - 16384) * 256 + tid;
        float4 v = ((const float4*)W_ih)[i];
        ushort4 o; o.x = f2bf(v.x); o.y = f2bf(v.y); o.z = f2bf(v.z); o.w = f2bf(v.w);
        ((ushort4*)wb)[i] = o;
    } else {
        int idx = (blk - 20480) * 256 + tid;   // 16*2336 = 37376
        if (idx < 37376) {
            int c = idx / 2336, k = idx - c * 2336;
            float v = (c < 10 && k < 2318) ? W_lin[c * 2318 + k] : 0.f;
            wlb[idx] = f2bf(v);
        }
    }
}

// ---------------- GEMM: Hb = bf16(tanh(x @ W_ih^T + b)) ----------------
// (unchanged from round 2 — 256x256 tile, BK=64, balanced 4-phase, counted
// vmcnt, setprio, XCD map 4rblk x 8cblk -> 4MB A L2-resident per XCD)

#define MFMA_(a, b, c) __builtin_amdgcn_mfma_f32_16x16x32_bf16(a, b, c, 0, 0, 0)

__device__ inline s16x8 frag_ld(const unsigned short* hbase, int row, int ksub, int quad) {
    int slot = (ksub * 4 + quad) ^ (row & 7);
    return *(const s16x8*)(hbase + row * 64 + slot * 8);
}

// stage one 8KB unit: 64 rows x 64 cols bf16, 1x16B load per thread
__device__ inline void stage_u(const unsigned short* __restrict__ gmat, int half,
                               int rowoff, int kt, unsigned short* lmat, int tid) {
    int r = tid >> 3, s = tid & 7;
    int lr = rowoff + r;
    int ks = (s ^ (lr & 7)) << 3;
    const unsigned short* gp = gmat + (size_t)(half * 128 + lr) * 2048 + kt * 64 + ks;
    __builtin_amdgcn_global_load_lds(
        (const __attribute__((address_space(1))) void*)gp,
        (__attribute__((address_space(3))) void*)(lmat + half * 8192 + lr * 64 + s * 8),
        16, 0, 0);
}

#define LOAD_B(ks)                                                       \
    b0 = frag_ld(Bh, bco +  0 + mrow, (ks), quad);                       \
    b1 = frag_ld(Bh, bco + 16 + mrow, (ks), quad);                       \
    b2 = frag_ld(Bh, bco + 32 + mrow, (ks), quad);                       \
    b3 = frag_ld(Bh, bco + 48 + mrow, (ks), quad);

#define LOAD_A(h, ks)                                                    \
    af0 = frag_ld(Ah, (h) * 64 +  0 + mrow, (ks), quad);                 \
    af1 = frag_ld(Ah, (h) * 64 + 16 + mrow, (ks), quad);                 \
    af2 = frag_ld(Ah, (h) * 64 + 32 + mrow, (ks), quad);                 \
    af3 = frag_ld(Ah, (h) * 64 + 48 + mrow, (ks), quad);

#define MFMA_H(hh)                                                       \
    acc[(hh)*4 + 0][0] = MFMA_(af0, b0, acc[(hh)*4 + 0][0]);             \
    acc[(hh)*4 + 0][1] = MFMA_(af0, b1, acc[(hh)*4 + 0][1]);             \
    acc[(hh)*4 + 0][2] = MFMA_(af0, b2, acc[(hh)*4 + 0][2]);             \
    acc[(hh)*4 + 0][3] = MFMA_(af0, b3, acc[(hh)*4 + 0][3]);             \
    acc[(hh)*4 + 1][0] = MFMA_(af1, b0, acc[(hh)*4 + 1][0]);             \
    acc[(hh)*4 + 1][1] = MFMA_(af1, b1, acc[(hh)*4 + 1][1]);             \
    acc[(hh)*4 + 1][2] = MFMA_(af1, b2, acc[(hh)*4 + 1][2]);             \
    acc[(hh)*4 + 1][3] = MFMA_(af1, b3, acc[(hh)*4 + 1][3]);             \
    acc[(hh)*4 + 2][0] = MFMA_(af2, b0, acc[(hh)*4 + 2][0]);             \
    acc[(hh)*4 + 2][1] = MFMA_(af2, b1, acc[(hh)*4 + 2][1]);             \
    acc[(hh)*4 + 2][2] = MFMA_(af2, b2, acc[(hh)*4 + 2][2]);             \
    acc[(hh)*4 + 2][3] = MFMA_(af2, b3, acc[(hh)*4 + 2][3]);             \
    acc[(hh)*4 + 3][0] = MFMA_(af3, b0, acc[(hh)*4 + 3][0]);             \
    acc[(hh)*4 + 3][1] = MFMA_(af3, b1, acc[(hh)*4 + 3][1]);             \
    acc[(hh)*4 + 3][2] = MFMA_(af3, b2, acc[(hh)*4 + 3][2]);             \
    acc[(hh)*4 + 3][3] = MFMA_(af3, b3, acc[(hh)*4 + 3][3]);

#define PHASE_CORE(hh)                                                   \
    __builtin_amdgcn_s_barrier();                                        \
    asm volatile("s_waitcnt lgkmcnt(0)" ::: "memory");                   \
    __builtin_amdgcn_s_setprio(1);                                       \
    MFMA_H(hh);                                                          \
    __builtin_amdgcn_s_setprio(0);

__global__ __launch_bounds__(512) void gemm_tanh_kernel(
    const unsigned short* __restrict__ A, const unsigned short* __restrict__ Bm,
    const float* __restrict__ b_ih, const float* __restrict__ b_hh,
    unsigned short* __restrict__ Hb)
{
    __shared__ __align__(16) unsigned short lds[2][2][16384];  // [buf][A/B][half*128*64]

    const int tid  = threadIdx.x;
    const int lane = tid & 63;
    const int wave = tid >> 6;
    const int wgid = blockIdx.x;
    const int xcd  = wgid & 7;
    const int idx  = wgid >> 3;          // 0..31
    const int rblk = xcd * 4 + (idx & 3);
    const int cblk = idx >> 2;           // 0..7
    const int row0 = rblk * 256;
    const int col0 = cblk * 256;
    const int wm   = wave >> 2;   // 0..1 : A half / 128-row block
    const int wn   = wave & 3;    // 0..3 : 64-col block
    const int quad = lane >> 4;
    const int mrow = lane & 15;
    const int NT   = 32;          // K tiles of 64

    const unsigned short* Ag = A  + (size_t)row0 * 2048;
    const unsigned short* Bg = Bm + (size_t)col0 * 2048;

    f32x4 acc[8][4];
#pragma unroll
    for (int i = 0; i < 8; ++i)
#pragma unroll
        for (int j = 0; j < 4; ++j) acc[i][j] = f32x4{0.f, 0.f, 0.f, 0.f};

    stage_u(Ag, 0, 0,  0, lds[0][0], tid);  stage_u(Ag, 0, 64, 0, lds[0][0], tid);
    stage_u(Ag, 1, 0,  0, lds[0][0], tid);  stage_u(Ag, 1, 64, 0, lds[0][0], tid);
    stage_u(Bg, 0, 0,  0, lds[0][1], tid);  stage_u(Bg, 0, 64, 0, lds[0][1], tid);
    stage_u(Bg, 1, 0,  0, lds[0][1], tid);  stage_u(Bg, 1, 64, 0, lds[0][1], tid);
    stage_u(Bg, 0, 0,  1, lds[1][1], tid);  stage_u(Bg, 0, 64, 1, lds[1][1], tid);
    stage_u(Ag, 0, 0,  1, lds[1][0], tid);  stage_u(Ag, 1, 0,  1, lds[1][0], tid);
    asm volatile("s_waitcnt vmcnt(4)" ::: "memory");  // tile0 resident
    __builtin_amdgcn_s_barrier();

    for (int t = 0; t < NT; ++t) {
        const int buf = t & 1;
        unsigned short* LA  = lds[buf][0];
        unsigned short* LB  = lds[buf][1];
        unsigned short* NLA = lds[buf ^ 1][0];
        unsigned short* NLB = lds[buf ^ 1][1];
        const unsigned short* Ah = LA + wm * 8192;
        const unsigned short* Bh = LB + (wn >> 1) * 8192;
        const int bco = (wn & 1) * 64;

        s16x8 b0, b1, b2, b3;
        s16x8 af0, af1, af2, af3;

        // ===== phase 1: B ks0 + A lo ks0 | stage t+1 A-bot + t+1 B-h1 =====
        LOAD_B(0);
        LOAD_A(0, 0);
        if (t + 1 < NT) {
            stage_u(Ag, 0, 64, t + 1, NLA, tid);
            stage_u(Ag, 1, 64, t + 1, NLA, tid);
            stage_u(Bg, 1, 0,  t + 1, NLB, tid);
            stage_u(Bg, 1, 64, t + 1, NLB, tid);
        }
        asm volatile("s_waitcnt lgkmcnt(4)" ::: "memory");  // B ks0 done
        PHASE_CORE(0);
        __builtin_amdgcn_s_barrier();

        // ===== phase 2: A hi ks0 =====
        LOAD_A(1, 0);
        PHASE_CORE(1);
        __builtin_amdgcn_s_barrier();

        // ===== phase 3: B ks1 + A lo ks1 =====
        LOAD_B(1);
        LOAD_A(0, 1);
        asm volatile("s_waitcnt lgkmcnt(4)" ::: "memory");  // B ks1 done
        PHASE_CORE(0);
        __builtin_amdgcn_s_barrier();

        // ===== phase 4: A hi ks1 | stage t+2 B-h0 + t+2 A-top; boundary =====
        LOAD_A(1, 1);
        if (t + 2 < NT) {
            stage_u(Bg, 0, 0,  t + 2, LB, tid);
            stage_u(Bg, 0, 64, t + 2, LB, tid);
            stage_u(Ag, 0, 0,  t + 2, LA, tid);
            stage_u(Ag, 1, 0,  t + 2, LA, tid);
        }
        PHASE_CORE(1);
        if (t + 2 < NT) {
            asm volatile("s_waitcnt vmcnt(4)" ::: "memory");   // t+1 resident
        } else if (t + 1 < NT) {
            asm volatile("s_waitcnt vmcnt(0)" ::: "memory");   // final drain
        }
        __builtin_amdgcn_s_barrier();
    }

    float bias[4];
#pragma unroll
    for (int j = 0; j < 4; ++j) {
        int gc = col0 + wn * 64 + j * 16 + mrow;
        bias[j] = b_ih[gc] + b_hh[gc];
    }
#pragma unroll
    for (int i = 0; i < 8; ++i) {
#pragma unroll
        for (int rr = 0; rr < 4; ++rr) {
            int grow = row0 + wm * 128 + i * 16 + quad * 4 + rr;
#pragma unroll
            for (int j = 0; j < 4; ++j) {
                int gc = col0 + wn * 64 + j * 16 + mrow;
                float v = acc[i][j][rr] + bias[j];
                Hb[(size_t)grow * 2048 + gc] = f2bf(fast_tanh(v));
            }
        }
    }
}

// ---------------- AvgPool1d(k=45,s=45): 8 rows/block, coalesced f-major out --
__global__ __launch_bounds__(256) void pool_kernel(
    const unsigned short* __restrict__ Hb, float* __restrict__ pooled_t) {
    __shared__ unsigned short hs[8 * 2048];  // 32 KB
    __shared__ float outs[45 * 8];
    int b0 = blockIdx.x * 8;
    int tid = threadIdx.x;
    const ushort4* src = (const ushort4*)(Hb + (size_t)b0 * 2048);
    ushort4* dst = (ushort4*)hs;
    for (int i = tid; i < 4096; i += 256) dst[i] = src[i];
    __syncthreads();
    for (int o = tid; o < 360; o += 256) {
        int f = o % 45, r = o / 45;
        const unsigned short* row = hs + r * 2048 + f * 45;
        float s = 0.f;
#pragma unroll
        for (int k = 0; k < 45; ++k) s += bf2f(row[k]);
        outs[f * 8 + r] = s * (1.0f / 45.0f);
    }
    __syncthreads();
    for (int o = tid; o < 360; o += 256) {
        int f = o >> 3, r = o & 7;
        pooled_t[f * 8192 + b0 + r] = outs[o];
    }
}

// ---------------- per-(feature,chunk) local dual prefix sum ------------------
// 360 blocks = 45 feats x 8 chunks of 1024. Fully parallel, float4-coalesced.
// Writes LOCAL inclusive prefixes (cs_t/cs2_t) + per-chunk totals (sums1/2);
// the 8-element chunk-base scan is folded into final_kernel's prologue.
__global__ __launch_bounds__(256) void scan_kernel(
    const float* __restrict__ pooled_t,
    float* __restrict__ cs_t, float* __restrict__ cs2_t,
    float* __restrict__ sums1, float* __restrict__ sums2) {
    __shared__ float t1[256], t2[256];
    int f  = blockIdx.x >> 3;
    int ch = blockIdx.x & 7;
    int tid = threadIdx.x;
    const float* p = pooled_t + f * 8192 + ch * 1024;
    float4 v = ((const float4*)p)[tid];
    float q1[4], q2[4];
    q1[0] = v.x;          q2[0] = v.x * v.x;
    q1[1] = q1[0] + v.y;  q2[1] = q2[0] + v.y * v.y;
    q1[2] = q1[1] + v.z;  q2[2] = q2[1] + v.z * v.z;
    q1[3] = q1[2] + v.w;  q2[3] = q2[2] + v.w * v.w;
    float s1 = q1[3], s2 = q2[3];
    t1[tid] = s1; t2[tid] = s2;
    __syncthreads();
    for (int d = 1; d < 256; d <<= 1) {
        float a1 = (tid >= d) ? t1[tid - d] : 0.f;
        float a2 = (tid >= d) ? t2[tid - d] : 0.f;
        __syncthreads();
        t1[tid] += a1; t2[tid] += a2;
        __syncthreads();
    }
    float r1 = t1[tid] - s1, r2 = t2[tid] - s2;  // exclusive offsets
    float4 o1, o2;
    o1.x = r1 + q1[0]; o1.y = r1 + q1[1]; o1.z = r1 + q1[2]; o1.w = r1 + q1[3];
    o2.x = r2 + q2[0]; o2.y = r2 + q2[1]; o2.z = r2 + q2[2]; o2.w = r2 + q2[3];
    ((float4*)(cs_t  + f * 8192 + ch * 1024))[tid] = o1;
    ((float4*)(cs2_t + f * 8192 + ch * 1024))[tid] = o2;
    if (tid == 255) {
        sums1[f * 8 + ch] = t1[255];
        sums2[f * 8 + ch] = t2[255];
    }
}

// ---------------- final: MFMA GEMM [Hb|est](8192x2336) @ Wb^T(16x2336) -------
// 512 blocks x 16 rows, 4 waves = 4-way K split (2 blocks/CU, 8 waves/CU for
// latency hiding). Chunk-base prefix (8 elems per feature) computed in LDS.
#define ESTRIDE 290
__global__ __launch_bounds__(256) void final_kernel(
    const unsigned short* __restrict__ Hb,
    const float* __restrict__ cs_t, const float* __restrict__ cs2_t,
    const float* __restrict__ sums1, const float* __restrict__ sums2,
    const unsigned short* __restrict__ Wb, const float* __restrict__ b_lin,
    float* __restrict__ out) {
    __shared__ unsigned short Es[16 * ESTRIDE];  // 9.1 KB
    __shared__ float eb1[45 * 8], eb2[45 * 8];   // 2.8 KB chunk bases (exclusive)
    __shared__ float comb[4][16][17];            // 4.3 KB
    int tid = threadIdx.x;
    int lane = tid & 63;
    int wave = tid >> 6;
    int b0 = blockIdx.x * 16;

    if (tid < 45) {
        float a = 0.f, b = 0.f;
#pragma unroll
        for (int c = 0; c < 8; ++c) {
            eb1[tid * 8 + c] = a; a += sums1[tid * 8 + c];
            eb2[tid * 8 + c] = b; b += sums2[tid * 8 + c];
        }
    }
    __syncthreads();

    // est tile: (f,j,r) -> mean/var from local prefixes + chunk bases
    for (int i = tid; i < 135 * 16; i += 256) {
        int fj = i >> 4, r = i & 15;
        int f = fj / 3, j = fj - 3 * f;
        int b = b0 + r;
        int L = (j == 0) ? 32 : (j == 1) ? 128 : 512;
        const float* c1 = cs_t + f * 8192;
        const float* c2 = cs2_t + f * 8192;
        float a1 = c1[b] + eb1[f * 8 + (b >> 10)];
        float a2 = c2[b] + eb2[f * 8 + (b >> 10)];
        float p1 = 0.f, p2 = 0.f;
        if (b >= L) {
            int ix = b - L;
            p1 = c1[ix] + eb1[f * 8 + (ix >> 10)];
            p2 = c2[ix] + eb2[f * 8 + (ix >> 10)];
        }
        float cnt = (float)((b + 1 < L) ? (b + 1) : L);
        float m = (a1 - p1) / cnt;
        float v = (a2 - p2) / cnt - m * m;
        int d0 = f * 6 + j * 2;
        Es[r * ESTRIDE + d0]     = f2bf(m);
        Es[r * ESTRIDE + d0 + 1] = f2bf(v);
    }
    // zero pad d in [270, 288)
    for (int i = tid; i < 16 * 18; i += 256) {
        int r = i / 18, d = 270 + i % 18;
        Es[r * ESTRIDE + d] = 0;
    }
    __syncthreads();

    const int kh = wave;          // 0..3 : K quarter (512 each)
    const int quad = lane >> 4;
    const int mrow = lane & 15;

    f32x4 acc = f32x4{0.f, 0.f, 0.f, 0.f};
    const unsigned short* arow = Hb + (size_t)(b0 + mrow) * 2048 + kh * 512 + quad * 8;
    const unsigned short* brow = Wb + (size_t)mrow * 2336 + kh * 512 + quad * 8;
#pragma unroll 4
    for (int k = 0; k < 512; k += 32) {
        s16x8 a = *(const s16x8*)(arow + k);
        s16x8 b = *(const s16x8*)(brow + k);
        acc = __builtin_amdgcn_mfma_f32_16x16x32_bf16(a, b, acc, 0, 0, 0);
    }
    if (kh == 3) {
        const unsigned short* erow = Es + mrow * ESTRIDE + quad * 8;
        const unsigned short* wrow = Wb + (size_t)mrow * 2336 + 2048 + quad * 8;
#pragma unroll
        for (int k = 0; k < 288; k += 32) {
            s16x8 a = *(const s16x8*)(erow + k);
            s16x8 b = *(const s16x8*)(wrow + k);
            acc = __builtin_amdgcn_mfma_f32_16x16x32_bf16(a, b, acc, 0, 0, 0);
        }
    }

#pragma unroll
    for (int r = 0; r < 4; ++r) comb[kh][quad * 4 + r][mrow] = acc[r];
    __syncthreads();

    {
        int r = tid >> 4, c = tid & 15;
        float v = comb[0][r][c] + comb[1][r][c] + comb[2][r][c] + comb[3][r][c];
        comb[0][r][c] = v;   // each thread reads/writes only its own (r,c)
    }
    __syncthreads();

    if (tid < 16) {
        float lg[10];
        float mx = -1e30f;
#pragma unroll
        for (int c = 0; c < 10; ++c) {
            lg[c] = comb[0][tid][c] + b_lin[c];
            mx = fmaxf(mx, lg[c]);
        }
        float s = 0.f;
#pragma unroll
        for (int c = 0; c < 10; ++c) { lg[c] = expf(lg[c] - mx); s += lg[c]; }
        float inv = 1.0f / s;
#pragma unroll
        for (int c = 0; c < 10; ++c) out[(size_t)(b0 + tid) * 10 + c] = lg[c] * inv;
    }
}

// ---------------- launch ----------------
extern "C" void kernel_launch(void* const* d_in, const int* in_sizes, int n_in,
                              void* d_out, int out_size, void* d_ws, size_t ws_size,
                              hipStream_t stream) {
    const float* x     = (const float*)d_in[0];   // (8192,1,2048)
    const float* W_ih  = (const float*)d_in[1];   // (2048,2048)
    // d_in[2] = W_hh unused: h0 == 0 so the recurrent term vanishes
    const float* b_ih  = (const float*)d_in[3];
    const float* b_hh  = (const float*)d_in[4];
    const float* W_lin = (const float*)d_in[5];   // (10, 2318)
    const float* b_lin = (const float*)d_in[6];
    float* out = (float*)d_out;

    char* ws = (char*)d_ws;
    unsigned short* xb  = (unsigned short*)(ws);                 // 33554432 B
    unsigned short* wb  = (unsigned short*)(ws + 33554432);      //  8388608 B
    unsigned short* Hb  = (unsigned short*)(ws + 41943040);      // 33554432 B
    float* pooled_t     = (float*)(ws + 75497472);               //  1474560 B
    float* cs_t         = (float*)(ws + 76972032);               //  1474560 B
    float* cs2_t        = (float*)(ws + 78446592);               //  1474560 B
    unsigned short* wlb = (unsigned short*)(ws + 79921152);      //    74752 B
    float* sums1        = (float*)(ws + 79995904);               //     1440 B
    float* sums2        = (float*)(ws + 79997344);               //     1440 B (~80 MB)

    cvtprep_kernel<<<20626, 256, 0, stream>>>(x, W_ih, W_lin, xb, wb, wlb);
    gemm_tanh_kernel<<<256, 512, 0, stream>>>(xb, wb, b_ih, b_hh, Hb);
    pool_kernel<<<1024, 256, 0, stream>>>(Hb, pooled_t);
    scan_kernel<<<360, 256, 0, stream>>>(pooled_t, cs_t, cs2_t, sums1, sums2);
    final_kernel<<<512, 256, 0, stream>>>(Hb, cs_t, cs2_t, sums1, sums2, wlb, b_lin, out);
}